// Round 10
// baseline (227.548 us; speedup 1.0000x reference)
//
#include <hip/hip_runtime.h>

#define GRIDN   16
#define KMAX    32
#define NPER    2048
#define DFEAT   256
#define RCELLS  256     // GRIDN*GRIDN
#define XYS     35      // ints per xy row (3 header + 32 inds)

// ---------------------------------------------------------------------------
// Single fused kernel: one wave = one xy row (cell). Header+indices in SGPRs
// via readlane; gather rounds [8,4,4,4,4,4,4] behind wave-uniform scalar
// branches (E[slots]=18.5 vs 16.5 ideal); masked slots redirect to row 0
// (L1-hot). Result written DIRECTLY to out[b][d][cell] as 4 scalar stores
// per lane — scattered 4B stores, but L2 merges them (R1/R2: WRITE_SIZE
// stayed exactly 16 MB under scatter). This eliminates the ws round-trip
// (16.8 MB pipe bytes) and the phase-2 launch entirely.
// ---------------------------------------------------------------------------
__global__ __launch_bounds__(256) void spp_pool_fused(
    const float* __restrict__ F,     // (B*NPER, DFEAT)
    const int*   __restrict__ xy,    // (B*NPER, XYS)
    float*       __restrict__ out,   // (B, DFEAT, RCELLS)
    int B)
{
    int bx = blockIdx.x;
    int b, chunk;
    if ((B & 7) == 0) {
        // batch-major per XCD (neutral but harmless; keeps L2 window tight)
        int xcd = bx & 7;
        int s   = bx >> 3;
        b     = xcd * (B >> 3) + (s >> 6);
        chunk = s & 63;
    } else {
        b     = bx >> 6;
        chunk = bx & 63;
    }

    int tid  = threadIdx.x;
    int wv   = tid >> 6;
    int lane = tid & 63;
    int r    = chunk * 4 + wv;           // rows 0..255 carry all cells

    const int* xr = xy + ((size_t)b * NPER + r) * XYS;
    int hv = xr[lane < XYS ? lane : 0];  // one coalesced 140B row load

    int row = __builtin_amdgcn_readlane(hv, 0);   // SGPR header
    int col = __builtin_amdgcn_readlane(hv, 1);
    int cnt = __builtin_amdgcn_readlane(hv, 2);
    if (row < 0) return;                          // wave-uniform
    if (cnt > KMAX) cnt = KMAX;

    const float4* Fb4 = (const float4*)(F + (size_t)b * NPER * DFEAT);
    float4 acc = make_float4(0.f, 0.f, 0.f, 0.f);

    {   // round A: slots 0..7, unconditional (cnt >= 1 always)
        float4 f[8];
        #pragma unroll
        for (int j = 0; j < 8; ++j) {
            int raw = __builtin_amdgcn_readlane(hv, 3 + j);
            int idx = (j < cnt) ? raw : 0;          // scalar select; row-0 L1-hot
            f[j] = Fb4[(size_t)idx * 64 + lane];    // 1KB/wave coalesced
        }
        #pragma unroll
        for (int j = 0; j < 8; ++j) {
            float w = (j < cnt) ? 1.f : 0.f;
            acc.x += w * f[j].x; acc.y += w * f[j].y;
            acc.z += w * f[j].z; acc.w += w * f[j].w;
        }
    }
    // rounds of 4: bases 8..28, each skipped wave-uniformly when exhausted
    #pragma unroll
    for (int base = 8; base < KMAX; base += 4) {
        if (cnt > base) {
            float4 f[4];
            #pragma unroll
            for (int j = 0; j < 4; ++j) {
                int raw = __builtin_amdgcn_readlane(hv, 3 + base + j);
                int idx = (base + j < cnt) ? raw : 0;
                f[j] = Fb4[(size_t)idx * 64 + lane];
            }
            #pragma unroll
            for (int j = 0; j < 4; ++j) {
                float w = (base + j < cnt) ? 1.f : 0.f;
                acc.x += w * f[j].x; acc.y += w * f[j].y;
                acc.z += w * f[j].z; acc.w += w * f[j].w;
            }
        }
    }

    float inv = 1.f / (float)(cnt > 0 ? cnt : 1);
    int cell  = row * GRIDN + col;

    // direct transposed store: lane owns d = lane*4 .. lane*4+3
    float* ob = out + (size_t)b * DFEAT * RCELLS + (size_t)(lane * 4) * RCELLS + cell;
    ob[0 * RCELLS] = acc.x * inv;
    ob[1 * RCELLS] = acc.y * inv;
    ob[2 * RCELLS] = acc.z * inv;
    ob[3 * RCELLS] = acc.w * inv;
}

extern "C" void kernel_launch(void* const* d_in, const int* in_sizes, int n_in,
                              void* d_out, int out_size, void* d_ws, size_t ws_size,
                              hipStream_t stream) {
    const float* F   = (const float*)d_in[0];
    const int*   xy  = (const int*)d_in[1];
    float*       out = (float*)d_out;
    int B = in_sizes[2];                 // nodes_per_graph length = 64

    hipLaunchKernelGGL(spp_pool_fused, dim3(B * 64), dim3(256), 0, stream,
                       F, xy, out, B);
}